// Round 13
// baseline (54.641 us; speedup 1.0000x reference)
//
#include <hip/hip_runtime.h>

#define DIM 128
#define NHEAD 64
#define NROT 8128
#define NSEG28 28
#define MHEAD28 57344          // sum n_s^2, 28 sub-chunks
#define KAC 168                // compose LDS k-dim (128 data + zero pad)
#define CSROWS 64              // mono fallback staging

typedef float f4 __attribute__((ext_vector_type(4)));
typedef short bf8 __attribute__((ext_vector_type(8)));
typedef unsigned short u16;

// 28 sub-chunk segments: rotations {(a0+t, j): j in [j0, j0+nj)}, support
// {a0..a0+7} u [j0, j0+nj). Chunk0 of each group also carries the 28 intra rots.
__device__ const int S_A0[NSEG28] = {0,0,0,8,8,8,16,16,16,24,24,32,32,40,40,
                                     48,48,56,56,64,64,72,80,88,96,104,112,120};
__device__ const int S_J0[NSEG28] = {8,56,104,16,64,112,24,72,120,32,80,40,88,48,96,
                                     56,104,64,112,72,120,80,88,96,104,112,120,128};
__device__ const int S_NJ[NSEG28] = {48,48,24,48,48,16,48,48,8,48,48,48,40,48,32,
                                     48,24,48,16,48,8,48,40,32,24,16,8,0};
__device__ const int S_OFF[NSEG28] = {0,3136,6272,7296,10432,13568,14144,17280,20416,
                                      20672,23808,26944,30080,32384,35520,37120,40256,
                                      41280,44416,44992,48128,48384,51520,53824,55424,
                                      56448,57024,57280};
__device__ const int S_INTRA[NSEG28] = {1,0,0,1,0,0,1,0,0,1,0,1,0,1,0,
                                        1,0,1,0,1,0,1,1,1,1,1,1,1};

// |theta| <= ~0.06: degree-5/4 Taylor, error ~1e-11
__device__ __forceinline__ void sincos_poly(float x, float& sn, float& cn) {
    float x2 = x * x;
    sn = x * fmaf(x2, fmaf(x2, 8.33333333e-3f, -1.66666667e-1f), 1.0f);
    cn = fmaf(x2, fmaf(x2, 4.16666667e-2f, -0.5f), 1.0f);
}

__device__ __forceinline__ u16 f2bf(float v) {          // RNE f32 -> bf16 bits
    unsigned b = __float_as_uint(v);
    b += 0x7FFF + ((b >> 16) & 1);
    return (u16)(b >> 16);
}
__device__ __forceinline__ float bf2f(u16 h) {
    return __uint_as_float(((unsigned)h) << 16);
}

struct Row { f4 q0, q1, q2, q3; };   // 8 (c,s) pairs for one trailing row

__device__ __forceinline__ void ldrow_u(Row& R, const float* p) {
    const f4* c4 = (const f4*)p;
    R.q0 = c4[0]; R.q1 = c4[1]; R.q2 = c4[2]; R.q3 = c4[3];
}

// v-chain for one trailing row: v_in known constant, p in registers.
__device__ __forceinline__ float rowv(const Row& R, float p[8], float v) {
#define ROT2(c, s, T) { float pv = p[T]; float nv = fmaf((c), v, -((s) * pv)); \
                        p[T] = fmaf((s), v, (c) * pv); v = nv; }
    ROT2(R.q0.x, R.q0.y, 0) ROT2(R.q0.z, R.q0.w, 1)
    ROT2(R.q1.x, R.q1.y, 2) ROT2(R.q1.z, R.q1.w, 3)
    ROT2(R.q2.x, R.q2.y, 4) ROT2(R.q2.z, R.q2.w, 5)
    ROT2(R.q3.x, R.q3.y, 6) ROT2(R.q3.z, R.q3.w, 7)
#undef ROT2
    return v;
}

__device__ __forceinline__ void store_bf(u16* oh, u16* ol, int idx, float v, bool act) {
    u16 h = f2bf(v);
    u16 l = f2bf(v - bf2f(h));
    if (act) { oh[idx] = h; ol[idx] = l; }
}

// ==== Phase 1: Q-less sub-chunk chain (28 units/head, max 48 serial rows) ====
__global__ __launch_bounds__(64, 1)
void chain28(const float* __restrict__ th_all,
             u16* __restrict__ MhW, u16* __restrict__ MlW)
{
    __shared__ __align__(16) float csx[56 + 48 * 16];   // 3.3 KB

    const int lane = threadIdx.x;
    const int head = blockIdx.x & 63;        // XCD = head%8 for producer+consumer
    const int s    = blockIdx.x >> 6;
    const int a0 = S_A0[s], j0 = S_J0[s], nj = S_NJ[s], n = 8 + nj;
    const bool intra = S_INTRA[s] != 0;
    const float* __restrict__ th = th_all + head * NROT;
    u16* __restrict__ oh = MhW + (size_t)head * MHEAD28 + S_OFF[s];
    u16* __restrict__ ol = MlW + (size_t)head * MHEAD28 + S_OFF[s];
    const bool cact = lane < n;
    const int ne = 8 * nj;
    const int d1 = j0 - a0 - 1;              // theta: idx = base_i + d1 - t + jr

    // batched theta loads (independent -> one latency exposure)
    float thx[6];
    #pragma unroll
    for (int it = 0; it < 6; ++it) {
        if (it * 64 < ne) {
            int e = lane + it * 64;
            int t = e & 7, jr = e >> 3;
            int i = a0 + t;
            thx[it] = th[((i * (255 - i)) >> 1) + d1 - t + jr];
        }
    }
    float thi = 0.0f;
    if (intra && lane < 28) {
        int t1 = 0, rem = lane;
        while (rem >= 7 - t1) { rem -= 7 - t1; ++t1; }
        int t2 = t1 + 1 + rem;
        int i  = a0 + t1;
        thi = th[((i * (255 - i)) >> 1) + (t2 - t1 - 1)];
    }
    #pragma unroll
    for (int it = 0; it < 6; ++it) {
        if (it * 64 < ne) {
            int e = lane + it * 64;
            float sn, cn; sincos_poly(thx[it], sn, cn);
            csx[56 + 2 * e] = cn; csx[56 + 2 * e + 1] = sn;
        }
    }
    if (intra && lane < 28) {
        float sn, cn; sincos_poly(thi, sn, cn);
        csx[2 * lane] = cn; csx[2 * lane + 1] = sn;
    }
    __syncthreads();

    float p[8];
    #pragma unroll
    for (int t = 0; t < 8; ++t) p[t] = (lane == t) ? 1.0f : 0.0f;

    if (intra) {                             // 28 pivot-pivot rotations
        int idx = 0;
        #pragma unroll
        for (int t1 = 0; t1 < 8; ++t1) {
            #pragma unroll
            for (int t2 = t1 + 1; t2 < 8; ++t2) {
                float c = csx[2 * idx], sn = csx[2 * idx + 1];
                float pa = p[t1];
                p[t1] = fmaf(c, pa,    sn * p[t2]);
                p[t2] = fmaf(c, p[t2], -(sn * pa));
                ++idx;
            }
        }
    }

    if (nj > 0) {
        const float* cs = csx + 56;
        const int jv = lane - 8;             // local trailing row where v_in = 1
        Row A0, A1, B0, B1;
        ldrow_u(A0, cs); ldrow_u(A1, cs + 16);
        #pragma unroll 1
        for (int r = 0; r < nj; r += 4) {
            ldrow_u(B0, cs + 16 * (r + 2)); ldrow_u(B1, cs + 16 * (r + 3));
            float v0 = rowv(A0, p, (r     == jv) ? 1.0f : 0.0f);
            float v1 = rowv(A1, p, (r + 1 == jv) ? 1.0f : 0.0f);
            store_bf(oh, ol, (8 + r)     * n + lane, v0, cact);
            store_bf(oh, ol, (8 + r + 1) * n + lane, v1, cact);
            if (r + 4 < nj) { ldrow_u(A0, cs + 16 * (r + 4));
                              ldrow_u(A1, cs + 16 * (r + 5)); }
            float v2 = rowv(B0, p, (r + 2 == jv) ? 1.0f : 0.0f);
            float v3 = rowv(B1, p, (r + 3 == jv) ? 1.0f : 0.0f);
            store_bf(oh, ol, (8 + r + 2) * n + lane, v2, cact);
            store_bf(oh, ol, (8 + r + 3) * n + lane, v3, cact);
        }
    }

    #pragma unroll
    for (int t = 0; t < 8; ++t)
        store_bf(oh, ol, t * n + lane, p[t], cact);
}

// ==== Phase 2: single-wave barrier-free MFMA compose ====
// Block = 1 wave = (head, 16-col slice). B-frags (A_old) register-cached per
// segment before any store; row-tiles looped with 2-stage M-frag prefetch.
__global__ __launch_bounds__(64, 1)
void compose_sw(const u16* __restrict__ MhA, const u16* __restrict__ MlA,
                float* __restrict__ out)
{
    __shared__ u16 AhT[16][KAC];             // 5.25 KB each; rows >=128 = zero pad
    __shared__ u16 AlT[16][KAC];

    const int lane = threadIdx.x;
    const int head = blockIdx.x & 63;        // all 8 slices -> same XCD as producer
    const int sl   = blockIdx.x >> 6;
    const int c0   = sl * 16;
    const u16* __restrict__ Mh = MhA + (size_t)head * MHEAD28;
    const u16* __restrict__ Ml = MlA + (size_t)head * MHEAD28;

    {   // zero k-pad, then A := embedded M0 (chunk 0 spans rows/cols [0,56))
        int c = lane & 15, rr = lane >> 4, cg = c0 + c;
        for (int k = DIM + rr; k < KAC; k += 4) { AhT[c][k] = 0; AlT[c][k] = 0; }
        for (int r = rr; r < DIM; r += 4) {
            u16 h, l;
            if (r < 56 && cg < 56) { h = Mh[r * 56 + cg]; l = Ml[r * 56 + cg]; }
            else                   { h = (r == cg) ? (u16)0x3F80 : (u16)0; l = 0; }
            AhT[c][r] = h; AlT[c][r] = l;
        }
    }
    // single wave: no barriers anywhere; compiler orders LDS via lgkmcnt

    const int fr = lane & 15;                // B col (LDS col) / C col / M row in tile
    const int fk = (lane >> 4) * 8;          // k-slice offset
    const int r4 = (lane >> 4) * 4;          // C row quad offset

    #pragma unroll 1
    for (int s = 1; s < NSEG28; ++s) {
        const int a0 = S_A0[s], j0 = S_J0[s], n = 8 + S_NJ[s];
        const u16* __restrict__ Msh = Mh + S_OFF[s];
        const u16* __restrict__ Msl = Ml + S_OFF[s];

        // B-fragments: tile-row-invariant; read ALL before any store (hazard-free)
        const int kk0 = fk, kk1 = 32 + fk;
        const int b0 = (kk0 < 8) ? (a0 + kk0) : ((kk0 < n) ? (j0 + kk0 - 8) : 128);
        const int b1 = (kk1 < 8) ? (a0 + kk1) : ((kk1 < n) ? (j0 + kk1 - 8) : 128);
        bf8 bh0 = *(const bf8*)&AhT[fr][b0];
        bf8 bl0 = *(const bf8*)&AlT[fr][b0];
        bf8 bh1 = *(const bf8*)&AhT[fr][b1]; // zero pad when kk1 >= n
        bf8 bl1 = *(const bf8*)&AlT[fr][b1];
        const bool two = n > 32;             // wave-uniform
        const int kc0 = (kk0 <= n - 8) ? kk0 : (n - 8);
        const int kc1 = (kk1 <= n - 8) ? kk1 : (n - 8);

        // row-tiles with 2-stage global prefetch
        bf8 ahA, alA, ahA1, alA1, ahB, alB, ahB1, alB1;
        {
            const int rAc = (fr < n) ? fr : (n - 1);
            ahA = *(const bf8*)&Msh[(size_t)rAc * n + kc0];
            alA = *(const bf8*)&Msl[(size_t)rAc * n + kc0];
            if (two) {
                ahA1 = *(const bf8*)&Msh[(size_t)rAc * n + kc1];
                alA1 = *(const bf8*)&Msl[(size_t)rAc * n + kc1];
            }
        }
        #pragma unroll 1
        for (int ro = 0; ro < n; ro += 16) {
            const bool have = (ro + 16) < n;
            if (have) {
                const int rN  = ro + 16 + fr;
                const int rNc = (rN < n) ? rN : (n - 1);
                ahB = *(const bf8*)&Msh[(size_t)rNc * n + kc0];
                alB = *(const bf8*)&Msl[(size_t)rNc * n + kc0];
                if (two) {
                    ahB1 = *(const bf8*)&Msh[(size_t)rNc * n + kc1];
                    alB1 = *(const bf8*)&Msl[(size_t)rNc * n + kc1];
                }
            }
            f4 acc = {0, 0, 0, 0};
            acc = __builtin_amdgcn_mfma_f32_16x16x32_bf16(ahA, bh0, acc, 0, 0, 0);
            acc = __builtin_amdgcn_mfma_f32_16x16x32_bf16(ahA, bl0, acc, 0, 0, 0);
            acc = __builtin_amdgcn_mfma_f32_16x16x32_bf16(alA, bh0, acc, 0, 0, 0);
            acc = __builtin_amdgcn_mfma_f32_16x16x32_bf16(alA, bl0, acc, 0, 0, 0);
            if (two) {
                acc = __builtin_amdgcn_mfma_f32_16x16x32_bf16(ahA1, bh1, acc, 0, 0, 0);
                acc = __builtin_amdgcn_mfma_f32_16x16x32_bf16(ahA1, bl1, acc, 0, 0, 0);
                acc = __builtin_amdgcn_mfma_f32_16x16x32_bf16(alA1, bh1, acc, 0, 0, 0);
                acc = __builtin_amdgcn_mfma_f32_16x16x32_bf16(alA1, bl1, acc, 0, 0, 0);
            }

            const int rowq = ro + r4;        // quad stays inside one range
            if (rowq < n) {
                const int rg = (rowq < 8) ? (a0 + rowq) : (j0 + rowq - 8);
                float v0 = acc[0], v1 = acc[1], v2 = acc[2], v3 = acc[3];
                u16 h0 = f2bf(v0), h1 = f2bf(v1), h2 = f2bf(v2), h3 = f2bf(v3);
                u16 l0 = f2bf(v0 - bf2f(h0)), l1 = f2bf(v1 - bf2f(h1));
                u16 l2 = f2bf(v2 - bf2f(h2)), l3 = f2bf(v3 - bf2f(h3));
                ushort4 hv; hv.x = h0; hv.y = h1; hv.z = h2; hv.w = h3;
                ushort4 lv; lv.x = l0; lv.y = l1; lv.z = l2; lv.w = l3;
                *(ushort4*)&AhT[fr][rg] = hv;
                *(ushort4*)&AlT[fr][rg] = lv;
            }
            ahA = ahB; alA = alB; ahA1 = ahB1; alA1 = alB1;
        }
    }

    {   // output: Q = Ah + Al
        int c = lane & 15, rr = lane >> 4;
        float* o = out + (size_t)head * (DIM * DIM) + c0;
        for (int r = rr; r < DIM; r += 4)
            o[r * DIM + c] = bf2f(AhT[c][r]) + bf2f(AlT[c][r]);
    }
}

// ==== Fallback: monolithic Q-in-LDS chain (proven R7 structure), tiny-ws only ====
#define QA(r, c) Q[(r)][ (c) ^ ((r) & 31) ]
#define ROTP(c, s, T, v) { float pt = p[T]; p[T] = fmaf((c), pt, (s) * (v)); \
                           (v) = fmaf((c), (v), -((s) * pt)); }
__device__ __forceinline__ void rot8q(const Row& r, float p[8], float& v) {
    ROTP(r.q0.x, r.q0.y, 0, v) ROTP(r.q0.z, r.q0.w, 1, v)
    ROTP(r.q1.x, r.q1.y, 2, v) ROTP(r.q1.z, r.q1.w, 3, v)
    ROTP(r.q2.x, r.q2.y, 4, v) ROTP(r.q2.z, r.q2.w, 5, v)
    ROTP(r.q3.x, r.q3.y, 6, v) ROTP(r.q3.z, r.q3.w, 7, v)
}

__global__ __launch_bounds__(64, 1)
void chain_mono(const float* __restrict__ th_all, float* __restrict__ outp)
{
    __shared__ float Q[DIM][64];
    __shared__ __align__(16) float csx[56 + CSROWS * 16];

    const int lane = threadIdx.x;
    const int head = blockIdx.x & 63;
    const int cb   = blockIdx.x >> 6;
    const int col_glob = cb * 64 + lane;
    const float* __restrict__ th = th_all + head * NROT;

    for (int r = 0; r < DIM; ++r)
        QA(r, lane) = (r == col_glob) ? 1.0f : 0.0f;

    #pragma unroll 1
    for (int g = 0; g < 16; ++g) {
        const int a0  = 8 * g;
        const int ntr = 120 - a0;
        float p[8];
        const int nsub = (ntr > CSROWS) ? 2 : 1;
        #pragma unroll 1
        for (int sub = 0; sub < nsub; ++sub) {
            const int r0 = sub * CSROWS;
            const int nr = (ntr - r0) < CSROWS ? (ntr - r0) : CSROWS;
            const int ne = 8 * nr;
            __syncthreads();
            float thx[8];
            #pragma unroll
            for (int it = 0; it < 8; ++it) {
                if (it * 64 < ne) {
                    int e = lane + it * 64;
                    int t = e & 7, jr = r0 + (e >> 3);
                    int i = a0 + t;
                    thx[it] = th[((i * (255 - i)) >> 1) + jr + 7 - t];
                }
            }
            float thi = 0.0f;
            if (sub == 0 && lane < 28) {
                int t1 = 0, rem = lane;
                while (rem >= 7 - t1) { rem -= 7 - t1; ++t1; }
                int t2 = t1 + 1 + rem;
                int i  = a0 + t1;
                thi = th[((i * (255 - i)) >> 1) + (t2 - t1 - 1)];
            }
            #pragma unroll
            for (int it = 0; it < 8; ++it) {
                if (it * 64 < ne) {
                    int e = lane + it * 64;
                    float sn, cn; sincos_poly(thx[it], sn, cn);
                    csx[56 + 2 * e] = cn; csx[56 + 2 * e + 1] = sn;
                }
            }
            if (sub == 0 && lane < 28) {
                float sn, cn; sincos_poly(thi, sn, cn);
                csx[2 * lane] = cn; csx[2 * lane + 1] = sn;
            }
            __syncthreads();

            if (sub == 0) {
                #pragma unroll
                for (int t = 0; t < 8; ++t) p[t] = QA(a0 + t, lane);
                int idx = 0;
                #pragma unroll
                for (int t1 = 0; t1 < 8; ++t1) {
                    #pragma unroll
                    for (int t2 = t1 + 1; t2 < 8; ++t2) {
                        float c = csx[2 * idx], sn = csx[2 * idx + 1];
                        float pa = p[t1];
                        p[t1] = fmaf(c, pa,    sn * p[t2]);
                        p[t2] = fmaf(c, p[t2], -(sn * pa));
                        ++idx;
                    }
                }
            }
            if (nr > 0) {
                const float* cs = csx + 56;
                const int base = a0 + 8 + r0;
                Row A0, A1, B0, B1;
                float vA0, vA1, vB0, vB1;
                auto ldpair = [&](Row& R, float& v, int r) {
                    ldrow_u(R, cs + 16 * r);
                    v = QA(base + r, lane);
                };
                ldpair(A0, vA0, 0); ldpair(A1, vA1, 1);
                #pragma unroll 1
                for (int r = 0; r < nr; r += 4) {
                    ldpair(B0, vB0, r + 2); ldpair(B1, vB1, r + 3);
                    rot8q(A0, p, vA0); rot8q(A1, p, vA1);
                    QA(base + r, lane)     = vA0;
                    QA(base + r + 1, lane) = vA1;
                    if (r + 4 < nr) { ldpair(A0, vA0, r + 4); ldpair(A1, vA1, r + 5); }
                    rot8q(B0, p, vB0); rot8q(B1, p, vB1);
                    QA(base + r + 2, lane) = vB0;
                    QA(base + r + 3, lane) = vB1;
                }
            }
        }
        #pragma unroll
        for (int t = 0; t < 8; ++t) QA(a0 + t, lane) = p[t];
    }

    __syncthreads();
    float* o = outp + head * (DIM * DIM) + col_glob;
    #pragma unroll 1
    for (int r = 0; r < DIM; ++r) o[r * DIM] = QA(r, lane);
}

extern "C" void kernel_launch(void* const* d_in, const int* in_sizes, int n_in,
                              void* d_out, int out_size, void* d_ws, size_t ws_size,
                              hipStream_t stream) {
    const float* thetas = (const float*)d_in[0];
    float* out = (float*)d_out;
    const size_t need = (size_t)NHEAD * MHEAD28 * 2 * sizeof(u16);  // 14.7 MB

    if (ws_size >= need) {
        u16* MhW = (u16*)d_ws;
        u16* MlW = MhW + (size_t)NHEAD * MHEAD28;
        chain28<<<dim3(NSEG28 * NHEAD), dim3(64), 0, stream>>>(thetas, MhW, MlW);
        compose_sw<<<dim3(8 * NHEAD), dim3(64), 0, stream>>>(MhW, MlW, out);
    } else {
        chain_mono<<<dim3(2 * NHEAD), dim3(64), 0, stream>>>(thetas, out);
    }
}

// Round 14
// 40.958 us; speedup vs baseline: 1.3341x; 1.3341x over previous
//
#include <hip/hip_runtime.h>

#define DIM 128
#define NHEAD 64
#define NROT 8128
#define NSEG28 28
#define MHEAD28 57344          // sum n_s^2, 28 sub-chunks
#define KAC 168                // compose LDS k-dim (128 data + zero pad)
#define CSROWS 64              // mono fallback staging

typedef float f4 __attribute__((ext_vector_type(4)));
typedef short bf8 __attribute__((ext_vector_type(8)));
typedef unsigned short u16;

// 28 sub-chunk segments: rotations {(a0+t, j): j in [j0, j0+nj)}, support
// {a0..a0+7} u [j0, j0+nj). Chunk0 of each group also carries the 28 intra rots.
__device__ const int S_A0[NSEG28] = {0,0,0,8,8,8,16,16,16,24,24,32,32,40,40,
                                     48,48,56,56,64,64,72,80,88,96,104,112,120};
__device__ const int S_J0[NSEG28] = {8,56,104,16,64,112,24,72,120,32,80,40,88,48,96,
                                     56,104,64,112,72,120,80,88,96,104,112,120,128};
__device__ const int S_NJ[NSEG28] = {48,48,24,48,48,16,48,48,8,48,48,48,40,48,32,
                                     48,24,48,16,48,8,48,40,32,24,16,8,0};
__device__ const int S_OFF[NSEG28] = {0,3136,6272,7296,10432,13568,14144,17280,20416,
                                      20672,23808,26944,30080,32384,35520,37120,40256,
                                      41280,44416,44992,48128,48384,51520,53824,55424,
                                      56448,57024,57280};
__device__ const int S_INTRA[NSEG28] = {1,0,0,1,0,0,1,0,0,1,0,1,0,1,0,
                                        1,0,1,0,1,0,1,1,1,1,1,1,1};

// |theta| <= ~0.06: degree-5/4 Taylor, error ~1e-11
__device__ __forceinline__ void sincos_poly(float x, float& sn, float& cn) {
    float x2 = x * x;
    sn = x * fmaf(x2, fmaf(x2, 8.33333333e-3f, -1.66666667e-1f), 1.0f);
    cn = fmaf(x2, fmaf(x2, 4.16666667e-2f, -0.5f), 1.0f);
}

__device__ __forceinline__ u16 f2bf(float v) {          // RNE f32 -> bf16 bits
    unsigned b = __float_as_uint(v);
    b += 0x7FFF + ((b >> 16) & 1);
    return (u16)(b >> 16);
}
__device__ __forceinline__ float bf2f(u16 h) {
    return __uint_as_float(((unsigned)h) << 16);
}

struct Row { f4 q0, q1, q2, q3; };   // 8 (c,s) pairs for one trailing row

__device__ __forceinline__ void ldrow_u(Row& R, const float* p) {
    const f4* c4 = (const f4*)p;
    R.q0 = c4[0]; R.q1 = c4[1]; R.q2 = c4[2]; R.q3 = c4[3];
}

// v-chain for one trailing row: v_in known constant, p in registers.
__device__ __forceinline__ float rowv(const Row& R, float p[8], float v) {
#define ROT2(c, s, T) { float pv = p[T]; float nv = fmaf((c), v, -((s) * pv)); \
                        p[T] = fmaf((s), v, (c) * pv); v = nv; }
    ROT2(R.q0.x, R.q0.y, 0) ROT2(R.q0.z, R.q0.w, 1)
    ROT2(R.q1.x, R.q1.y, 2) ROT2(R.q1.z, R.q1.w, 3)
    ROT2(R.q2.x, R.q2.y, 4) ROT2(R.q2.z, R.q2.w, 5)
    ROT2(R.q3.x, R.q3.y, 6) ROT2(R.q3.z, R.q3.w, 7)
#undef ROT2
    return v;
}

__device__ __forceinline__ void store_bf(u16* oh, u16* ol, int idx, float v, bool act) {
    u16 h = f2bf(v);
    u16 l = f2bf(v - bf2f(h));
    if (act) { oh[idx] = h; ol[idx] = l; }
}

// ==== Phase 1: Q-less sub-chunk chain (28 units/head, max 48 serial rows) ====
__global__ __launch_bounds__(64, 1)
void chain28(const float* __restrict__ th_all,
             u16* __restrict__ MhW, u16* __restrict__ MlW)
{
    __shared__ __align__(16) float csx[56 + 48 * 16];   // 3.3 KB

    const int lane = threadIdx.x;
    const int head = blockIdx.x & 63;        // XCD = head%8 for producer+consumer
    const int s    = blockIdx.x >> 6;
    const int a0 = S_A0[s], j0 = S_J0[s], nj = S_NJ[s], n = 8 + nj;
    const bool intra = S_INTRA[s] != 0;
    const float* __restrict__ th = th_all + head * NROT;
    u16* __restrict__ oh = MhW + (size_t)head * MHEAD28 + S_OFF[s];
    u16* __restrict__ ol = MlW + (size_t)head * MHEAD28 + S_OFF[s];
    const bool cact = lane < n;
    const int ne = 8 * nj;
    const int d1 = j0 - a0 - 1;              // theta: idx = base_i + d1 - t + jr

    // batched theta loads (independent -> one latency exposure)
    float thx[6];
    #pragma unroll
    for (int it = 0; it < 6; ++it) {
        if (it * 64 < ne) {
            int e = lane + it * 64;
            int t = e & 7, jr = e >> 3;
            int i = a0 + t;
            thx[it] = th[((i * (255 - i)) >> 1) + d1 - t + jr];
        }
    }
    float thi = 0.0f;
    if (intra && lane < 28) {
        int t1 = 0, rem = lane;
        while (rem >= 7 - t1) { rem -= 7 - t1; ++t1; }
        int t2 = t1 + 1 + rem;
        int i  = a0 + t1;
        thi = th[((i * (255 - i)) >> 1) + (t2 - t1 - 1)];
    }
    #pragma unroll
    for (int it = 0; it < 6; ++it) {
        if (it * 64 < ne) {
            int e = lane + it * 64;
            float sn, cn; sincos_poly(thx[it], sn, cn);
            csx[56 + 2 * e] = cn; csx[56 + 2 * e + 1] = sn;
        }
    }
    if (intra && lane < 28) {
        float sn, cn; sincos_poly(thi, sn, cn);
        csx[2 * lane] = cn; csx[2 * lane + 1] = sn;
    }
    __syncthreads();

    float p[8];
    #pragma unroll
    for (int t = 0; t < 8; ++t) p[t] = (lane == t) ? 1.0f : 0.0f;

    if (intra) {                             // 28 pivot-pivot rotations
        int idx = 0;
        #pragma unroll
        for (int t1 = 0; t1 < 8; ++t1) {
            #pragma unroll
            for (int t2 = t1 + 1; t2 < 8; ++t2) {
                float c = csx[2 * idx], sn = csx[2 * idx + 1];
                float pa = p[t1];
                p[t1] = fmaf(c, pa,    sn * p[t2]);
                p[t2] = fmaf(c, p[t2], -(sn * pa));
                ++idx;
            }
        }
    }

    if (nj > 0) {
        const float* cs = csx + 56;
        const int jv = lane - 8;             // local trailing row where v_in = 1
        Row A0, A1, B0, B1;
        ldrow_u(A0, cs); ldrow_u(A1, cs + 16);
        #pragma unroll 1
        for (int r = 0; r < nj; r += 4) {
            ldrow_u(B0, cs + 16 * (r + 2)); ldrow_u(B1, cs + 16 * (r + 3));
            float v0 = rowv(A0, p, (r     == jv) ? 1.0f : 0.0f);
            float v1 = rowv(A1, p, (r + 1 == jv) ? 1.0f : 0.0f);
            store_bf(oh, ol, (8 + r)     * n + lane, v0, cact);
            store_bf(oh, ol, (8 + r + 1) * n + lane, v1, cact);
            if (r + 4 < nj) { ldrow_u(A0, cs + 16 * (r + 4));
                              ldrow_u(A1, cs + 16 * (r + 5)); }
            float v2 = rowv(B0, p, (r + 2 == jv) ? 1.0f : 0.0f);
            float v3 = rowv(B1, p, (r + 3 == jv) ? 1.0f : 0.0f);
            store_bf(oh, ol, (8 + r + 2) * n + lane, v2, cact);
            store_bf(oh, ol, (8 + r + 3) * n + lane, v3, cact);
        }
    }

    #pragma unroll
    for (int t = 0; t < 8; ++t)
        store_bf(oh, ol, t * n + lane, p[t], cact);
}

// ==== Phase 2: 4-wave MFMA compose (R12 structure) + cross-segment M prefetch ====
__global__ __launch_bounds__(256, 1)
void compose4w(const u16* __restrict__ MhA, const u16* __restrict__ MlA,
               float* __restrict__ out)
{
    __shared__ u16 AhT[16][KAC];             // 5.25 KB each; rows >=128 = zero pad
    __shared__ u16 AlT[16][KAC];

    const int tid  = threadIdx.x;
    const int lane = tid & 63;
    const int w    = tid >> 6;
    const int head = blockIdx.x & 63;        // all 8 slices -> same XCD as producer
    const int sl   = blockIdx.x >> 6;
    const int c0   = sl * 16;
    const u16* __restrict__ Mh = MhA + (size_t)head * MHEAD28;
    const u16* __restrict__ Ml = MlA + (size_t)head * MHEAD28;

    {   // zero k-pad, then A := embedded M0 (chunk 0 spans rows/cols [0,56))
        int c = tid & 15, rr = tid >> 4, cg = c0 + c;
        for (int k = DIM + rr; k < KAC; k += 16) { AhT[c][k] = 0; AlT[c][k] = 0; }
        for (int r = rr; r < DIM; r += 16) {
            u16 h, l;
            if (r < 56 && cg < 56) { h = Mh[r * 56 + cg]; l = Ml[r * 56 + cg]; }
            else                   { h = (r == cg) ? (u16)0x3F80 : (u16)0; l = 0; }
            AhT[c][r] = h; AlT[c][r] = l;
        }
    }
    __syncthreads();

    const int fr = lane & 15;                // B col / C col / M row in tile
    const int fk = (lane >> 4) * 8;          // k-slice offset
    const int r4 = (lane >> 4) * 4;          // C row quad offset
    const int ro = 16 * w;                   // wave's row-tile base (1 tile/wave)

    // M-fragment loader for segment s (both k-chunks, address-clamped; any
    // clamped-duplicate M-frag multiplies a zero-pad B-frag -> contributes 0)
    auto ldM = [&](int s, bf8& ah0, bf8& al0, bf8& ah1, bf8& al1) {
        const int n = 8 + S_NJ[s];
        const u16* __restrict__ Msh = Mh + S_OFF[s];
        const u16* __restrict__ Msl = Ml + S_OFF[s];
        const int rA  = ro + fr;
        const int rAc = (rA < n) ? rA : (n - 1);
        const int kc0 = (fk <= n - 8) ? fk : (n - 8);
        const int kx  = 32 + fk;
        const int kc1 = (kx <= n - 8) ? kx : (n - 8);
        ah0 = *(const bf8*)&Msh[(size_t)rAc * n + kc0];
        al0 = *(const bf8*)&Msl[(size_t)rAc * n + kc0];
        ah1 = *(const bf8*)&Msh[(size_t)rAc * n + kc1];
        al1 = *(const bf8*)&Msl[(size_t)rAc * n + kc1];
    };

    bf8 cah0, cal0, cah1, cal1;              // current segment M-frags
    bf8 nah0, nal0, nah1, nal1;              // next segment M-frags
    ldM(1, cah0, cal0, cah1, cal1);

    #pragma unroll 1
    for (int s = 1; s < NSEG28; ++s) {
        const int a0 = S_A0[s], j0 = S_J0[s], n = 8 + S_NJ[s];

        // B-frags from A_old (LDS); zero-pad rows (>=128) kill k >= n exactly
        const int kk0 = fk, kx = 32 + fk;
        const int b0 = (kk0 < 8) ? (a0 + kk0) : ((kk0 < n) ? (j0 + kk0 - 8) : 128);
        const int b1 = (kx  < 8) ? (a0 + kx)  : ((kx  < n) ? (j0 + kx  - 8) : 128);
        bf8 bh0 = *(const bf8*)&AhT[fr][b0];
        bf8 bl0 = *(const bf8*)&AlT[fr][b0];
        bf8 bh1 = *(const bf8*)&AhT[fr][b1];
        bf8 bl1 = *(const bf8*)&AlT[fr][b1];

        // issue next segment's global M loads BEFORE the MFMAs: ~600 cyc of
        // MFMA+store+barrier cover the L2 latency (the R12 per-segment stall)
        if (s + 1 < NSEG28) ldM(s + 1, nah0, nal0, nah1, nal1);

        const bool act = ro < n;             // wave-uniform
        f4 acc = {0, 0, 0, 0};
        if (act) {
            acc = __builtin_amdgcn_mfma_f32_16x16x32_bf16(cah0, bh0, acc, 0, 0, 0);
            acc = __builtin_amdgcn_mfma_f32_16x16x32_bf16(cah0, bl0, acc, 0, 0, 0);
            acc = __builtin_amdgcn_mfma_f32_16x16x32_bf16(cal0, bh0, acc, 0, 0, 0);
            acc = __builtin_amdgcn_mfma_f32_16x16x32_bf16(cal0, bl0, acc, 0, 0, 0);
            acc = __builtin_amdgcn_mfma_f32_16x16x32_bf16(cah1, bh1, acc, 0, 0, 0);
            acc = __builtin_amdgcn_mfma_f32_16x16x32_bf16(cah1, bl1, acc, 0, 0, 0);
            acc = __builtin_amdgcn_mfma_f32_16x16x32_bf16(cal1, bh1, acc, 0, 0, 0);
            acc = __builtin_amdgcn_mfma_f32_16x16x32_bf16(cal1, bl1, acc, 0, 0, 0);
        }

        __syncthreads();                     // all reads of old A complete

        const int rowq = ro + r4;            // quad stays inside one range
        if (act && rowq < n) {
            const int rg = (rowq < 8) ? (a0 + rowq) : (j0 + rowq - 8);
            float v0 = acc[0], v1 = acc[1], v2 = acc[2], v3 = acc[3];
            u16 h0 = f2bf(v0), h1 = f2bf(v1), h2 = f2bf(v2), h3 = f2bf(v3);
            u16 l0 = f2bf(v0 - bf2f(h0)), l1 = f2bf(v1 - bf2f(h1));
            u16 l2 = f2bf(v2 - bf2f(h2)), l3 = f2bf(v3 - bf2f(h3));
            ushort4 hv; hv.x = h0; hv.y = h1; hv.z = h2; hv.w = h3;
            ushort4 lv; lv.x = l0; lv.y = l1; lv.z = l2; lv.w = l3;
            *(ushort4*)&AhT[fr][rg] = hv;
            *(ushort4*)&AlT[fr][rg] = lv;
        }
        __syncthreads();                     // new A visible

        cah0 = nah0; cal0 = nal0; cah1 = nah1; cal1 = nal1;
    }

    {   // output: Q = Ah + Al
        int c = tid & 15, rr = tid >> 4;
        float* o = out + (size_t)head * (DIM * DIM) + c0;
        for (int r = rr; r < DIM; r += 16)
            o[r * DIM + c] = bf2f(AhT[c][r]) + bf2f(AlT[c][r]);
    }
}

// ==== Fallback: monolithic Q-in-LDS chain (proven R7 structure), tiny-ws only ====
#define QA(r, c) Q[(r)][ (c) ^ ((r) & 31) ]
#define ROTP(c, s, T, v) { float pt = p[T]; p[T] = fmaf((c), pt, (s) * (v)); \
                           (v) = fmaf((c), (v), -((s) * pt)); }
__device__ __forceinline__ void rot8q(const Row& r, float p[8], float& v) {
    ROTP(r.q0.x, r.q0.y, 0, v) ROTP(r.q0.z, r.q0.w, 1, v)
    ROTP(r.q1.x, r.q1.y, 2, v) ROTP(r.q1.z, r.q1.w, 3, v)
    ROTP(r.q2.x, r.q2.y, 4, v) ROTP(r.q2.z, r.q2.w, 5, v)
    ROTP(r.q3.x, r.q3.y, 6, v) ROTP(r.q3.z, r.q3.w, 7, v)
}

__global__ __launch_bounds__(64, 1)
void chain_mono(const float* __restrict__ th_all, float* __restrict__ outp)
{
    __shared__ float Q[DIM][64];
    __shared__ __align__(16) float csx[56 + CSROWS * 16];

    const int lane = threadIdx.x;
    const int head = blockIdx.x & 63;
    const int cb   = blockIdx.x >> 6;
    const int col_glob = cb * 64 + lane;
    const float* __restrict__ th = th_all + head * NROT;

    for (int r = 0; r < DIM; ++r)
        QA(r, lane) = (r == col_glob) ? 1.0f : 0.0f;

    #pragma unroll 1
    for (int g = 0; g < 16; ++g) {
        const int a0  = 8 * g;
        const int ntr = 120 - a0;
        float p[8];
        const int nsub = (ntr > CSROWS) ? 2 : 1;
        #pragma unroll 1
        for (int sub = 0; sub < nsub; ++sub) {
            const int r0 = sub * CSROWS;
            const int nr = (ntr - r0) < CSROWS ? (ntr - r0) : CSROWS;
            const int ne = 8 * nr;
            __syncthreads();
            float thx[8];
            #pragma unroll
            for (int it = 0; it < 8; ++it) {
                if (it * 64 < ne) {
                    int e = lane + it * 64;
                    int t = e & 7, jr = r0 + (e >> 3);
                    int i = a0 + t;
                    thx[it] = th[((i * (255 - i)) >> 1) + jr + 7 - t];
                }
            }
            float thi = 0.0f;
            if (sub == 0 && lane < 28) {
                int t1 = 0, rem = lane;
                while (rem >= 7 - t1) { rem -= 7 - t1; ++t1; }
                int t2 = t1 + 1 + rem;
                int i  = a0 + t1;
                thi = th[((i * (255 - i)) >> 1) + (t2 - t1 - 1)];
            }
            #pragma unroll
            for (int it = 0; it < 8; ++it) {
                if (it * 64 < ne) {
                    int e = lane + it * 64;
                    float sn, cn; sincos_poly(thx[it], sn, cn);
                    csx[56 + 2 * e] = cn; csx[56 + 2 * e + 1] = sn;
                }
            }
            if (sub == 0 && lane < 28) {
                float sn, cn; sincos_poly(thi, sn, cn);
                csx[2 * lane] = cn; csx[2 * lane + 1] = sn;
            }
            __syncthreads();

            if (sub == 0) {
                #pragma unroll
                for (int t = 0; t < 8; ++t) p[t] = QA(a0 + t, lane);
                int idx = 0;
                #pragma unroll
                for (int t1 = 0; t1 < 8; ++t1) {
                    #pragma unroll
                    for (int t2 = t1 + 1; t2 < 8; ++t2) {
                        float c = csx[2 * idx], sn = csx[2 * idx + 1];
                        float pa = p[t1];
                        p[t1] = fmaf(c, pa,    sn * p[t2]);
                        p[t2] = fmaf(c, p[t2], -(sn * pa));
                        ++idx;
                    }
                }
            }
            if (nr > 0) {
                const float* cs = csx + 56;
                const int base = a0 + 8 + r0;
                Row A0, A1, B0, B1;
                float vA0, vA1, vB0, vB1;
                auto ldpair = [&](Row& R, float& v, int r) {
                    ldrow_u(R, cs + 16 * r);
                    v = QA(base + r, lane);
                };
                ldpair(A0, vA0, 0); ldpair(A1, vA1, 1);
                #pragma unroll 1
                for (int r = 0; r < nr; r += 4) {
                    ldpair(B0, vB0, r + 2); ldpair(B1, vB1, r + 3);
                    rot8q(A0, p, vA0); rot8q(A1, p, vA1);
                    QA(base + r, lane)     = vA0;
                    QA(base + r + 1, lane) = vA1;
                    if (r + 4 < nr) { ldpair(A0, vA0, r + 4); ldpair(A1, vA1, r + 5); }
                    rot8q(B0, p, vB0); rot8q(B1, p, vB1);
                    QA(base + r + 2, lane) = vB0;
                    QA(base + r + 3, lane) = vB1;
                }
            }
        }
        #pragma unroll
        for (int t = 0; t < 8; ++t) QA(a0 + t, lane) = p[t];
    }

    __syncthreads();
    float* o = outp + head * (DIM * DIM) + col_glob;
    #pragma unroll 1
    for (int r = 0; r < DIM; ++r) o[r * DIM] = QA(r, lane);
}

extern "C" void kernel_launch(void* const* d_in, const int* in_sizes, int n_in,
                              void* d_out, int out_size, void* d_ws, size_t ws_size,
                              hipStream_t stream) {
    const float* thetas = (const float*)d_in[0];
    float* out = (float*)d_out;
    const size_t need = (size_t)NHEAD * MHEAD28 * 2 * sizeof(u16);  // 14.7 MB

    if (ws_size >= need) {
        u16* MhW = (u16*)d_ws;
        u16* MlW = MhW + (size_t)NHEAD * MHEAD28;
        chain28<<<dim3(NSEG28 * NHEAD), dim3(64), 0, stream>>>(thetas, MhW, MlW);
        compose4w<<<dim3(8 * NHEAD), dim3(256), 0, stream>>>(MhW, MlW, out);
    } else {
        chain_mono<<<dim3(2 * NHEAD), dim3(64), 0, stream>>>(thetas, out);
    }
}

// Round 15
// 39.872 us; speedup vs baseline: 1.3704x; 1.0272x over previous
//
#include <hip/hip_runtime.h>

#define DIM 128
#define NHEAD 64
#define NROT 8128
#define NSEG7 7
#define MHEAD7 25600           // 6*64^2 + 32^2 per head
#define KAC 168                // compose LDS k-dim (128 data + zero pad)
#define CSROWS 64              // mono fallback staging

typedef float f4 __attribute__((ext_vector_type(4)));
typedef short bf8 __attribute__((ext_vector_type(8)));
typedef unsigned short u16;

// 7 segments, G=32 pivots: segment s = {rotations (a0+t, j): j in [j0, j0+nj)};
// chunk-0 of each pivot group also carries the 496 intra rotations.
// Support = {a0..a0+31} u [j0, j0+nj)  (n = 32 + nj <= 64).
__device__ const int C_A0[NSEG7]   = {0,0,0,32,32,64,96};
__device__ const int C_J0[NSEG7]   = {32,64,96,64,96,96,128};
__device__ const int C_NJ[NSEG7]   = {32,32,32,32,32,32,0};
__device__ const int C_N[NSEG7]    = {64,64,64,64,64,64,32};
__device__ const int C_OFF[NSEG7]  = {0,4096,8192,12288,16384,20480,24576};
__device__ const int C_INTRA[NSEG7]= {1,0,0,1,0,1,1};

// |theta| <= ~0.06: degree-5/4 Taylor, error ~1e-11
__device__ __forceinline__ void sincos_poly(float x, float& sn, float& cn) {
    float x2 = x * x;
    sn = x * fmaf(x2, fmaf(x2, 8.33333333e-3f, -1.66666667e-1f), 1.0f);
    cn = fmaf(x2, fmaf(x2, 4.16666667e-2f, -0.5f), 1.0f);
}

__device__ __forceinline__ u16 f2bf(float v) {          // RNE f32 -> bf16 bits
    unsigned b = __float_as_uint(v);
    b += 0x7FFF + ((b >> 16) & 1);
    return (u16)(b >> 16);
}
__device__ __forceinline__ float bf2f(u16 h) {
    return __uint_as_float(((unsigned)h) << 16);
}

__device__ __forceinline__ int tri_base(int i) {        // i*(255-i)/2
    return (i * (2 * DIM - 1 - i)) >> 1;
}

__device__ __forceinline__ void store_bf(u16* oh, u16* ol, int idx, float v, bool act) {
    u16 h = f2bf(v);
    u16 l = f2bf(v - bf2f(h));
    if (act) { oh[idx] = h; ol[idx] = l; }
}

// ==== Phase 1: Q-less G=32 chain (7 units/head, max 32 serial trailing rows) ====
__global__ __launch_bounds__(64, 1)
void chain7(const float* __restrict__ th_all,
            u16* __restrict__ MhW, u16* __restrict__ MlW)
{
    __shared__ __align__(16) float csx[992 + 32 * 64];  // 12.2 KB

    const int lane = threadIdx.x;
    const int head = blockIdx.x & 63;        // XCD = head%8, producer+consumer
    const int s    = blockIdx.x >> 6;
    const int a0 = C_A0[s], j0 = C_J0[s], nj = C_NJ[s], n = C_N[s];
    const bool intra = C_INTRA[s] != 0;
    const float* __restrict__ th = th_all + head * NROT;
    u16* __restrict__ oh = MhW + (size_t)head * MHEAD7 + C_OFF[s];
    u16* __restrict__ ol = MlW + (size_t)head * MHEAD7 + C_OFF[s];
    const bool cact = lane < n;
    const int ne = 32 * nj;                  // trailing rotations (1024 or 0)
    const int d1 = j0 - a0 - 1;

    // ---- staged theta loads (independent -> one latency exposure) ----
    float thx[16];
    #pragma unroll
    for (int it = 0; it < 16; ++it) {
        if (it * 64 < ne) {
            int e = lane + it * 64;
            int t = e & 31, r = e >> 5;
            thx[it] = th[tri_base(a0 + t) + d1 + r - t];
        }
    }
    float thi[8];
    #pragma unroll
    for (int it = 0; it < 8; ++it) {
        int e = lane + it * 64;
        if (intra && e < 496) {
            int t1 = 0, rem = e;
            while (rem >= 31 - t1) { rem -= 31 - t1; ++t1; }
            int t2 = t1 + 1 + rem;
            thi[it] = th[tri_base(a0 + t1) + (t2 - t1 - 1)];
        }
    }
    #pragma unroll
    for (int it = 0; it < 16; ++it) {
        if (it * 64 < ne) {
            int e = lane + it * 64;
            float sn, cn; sincos_poly(thx[it], sn, cn);
            csx[992 + 2 * e] = cn; csx[992 + 2 * e + 1] = sn;
        }
    }
    #pragma unroll
    for (int it = 0; it < 8; ++it) {
        int e = lane + it * 64;
        if (intra && e < 496) {
            float sn, cn; sincos_poly(thi[it], sn, cn);
            csx[2 * e] = cn; csx[2 * e + 1] = sn;
        }
    }
    __syncthreads();

    float p[32];
    #pragma unroll
    for (int t = 0; t < 32; ++t) p[t] = (lane == t) ? 1.0f : 0.0f;

    if (intra) {                             // 496 pivot-pivot rotations, static unroll
        f4 cc;
        int idx = 0;
        #pragma unroll
        for (int t1 = 0; t1 < 31; ++t1) {
            #pragma unroll
            for (int t2 = t1 + 1; t2 < 32; ++t2) {
                float c, sn;
                if ((idx & 1) == 0) { cc = *(const f4*)&csx[2 * idx]; c = cc.x; sn = cc.y; }
                else                { c = cc.z; sn = cc.w; }
                float pa = p[t1];
                p[t1] = fmaf(c, pa,    sn * p[t2]);
                p[t2] = fmaf(c, p[t2], -(sn * pa));
                ++idx;
            }
        }
    }

    if (nj > 0) {
        const float* cs = csx + 992;
        const int jv = lane - 32;            // local trailing row where v_in = 1
        #pragma unroll 2
        for (int r = 0; r < nj; ++r) {
            const f4* c4 = (const f4*)(cs + r * 64);
            f4 q[16];
            #pragma unroll
            for (int i = 0; i < 16; ++i) q[i] = c4[i];
            float v = (r == jv) ? 1.0f : 0.0f;
            #pragma unroll
            for (int t = 0; t < 32; t += 2) {
                f4 qq = q[t >> 1];
                { float pv = p[t];     float nv = fmaf(qq.x, v, -(qq.y * pv));
                  p[t]     = fmaf(qq.y, v, qq.x * pv); v = nv; }
                { float pv = p[t + 1]; float nv = fmaf(qq.z, v, -(qq.w * pv));
                  p[t + 1] = fmaf(qq.w, v, qq.z * pv); v = nv; }
            }
            store_bf(oh, ol, (32 + r) * n + lane, v, cact);
        }
    }

    #pragma unroll
    for (int t = 0; t < 32; ++t)             // pivot rows (local rows 0..31)
        store_bf(oh, ol, t * n + lane, p[t], cact);
}

// ==== Phase 2: 4-wave MFMA compose, 6 serial segments, 2-range row map ====
__global__ __launch_bounds__(256, 1)
void compose7(const u16* __restrict__ MhA, const u16* __restrict__ MlA,
              float* __restrict__ out)
{
    __shared__ u16 AhT[16][KAC];             // 5.25 KB each; rows >=128 = zero pad
    __shared__ u16 AlT[16][KAC];

    const int tid  = threadIdx.x;
    const int lane = tid & 63;
    const int w    = tid >> 6;
    const int head = blockIdx.x & 63;        // all 8 slices -> same XCD as producer
    const int sl   = blockIdx.x >> 6;
    const int c0   = sl * 16;
    const u16* __restrict__ Mh = MhA + (size_t)head * MHEAD7;
    const u16* __restrict__ Ml = MlA + (size_t)head * MHEAD7;

    {   // zero k-pad, then A := embedded M0 (segment 0 support = [0,64))
        int c = tid & 15, rr = tid >> 4, cg = c0 + c;
        for (int k = DIM + rr; k < KAC; k += 16) { AhT[c][k] = 0; AlT[c][k] = 0; }
        for (int r = rr; r < DIM; r += 16) {
            u16 h, l;
            if (r < 64 && cg < 64) { h = Mh[r * 64 + cg]; l = Ml[r * 64 + cg]; }
            else                   { h = (r == cg) ? (u16)0x3F80 : (u16)0; l = 0; }
            AhT[c][r] = h; AlT[c][r] = l;
        }
    }
    __syncthreads();

    const int fr = lane & 15;                // B col / C col / M row in tile
    const int fk = (lane >> 4) * 8;          // k-slice offset
    const int r4 = (lane >> 4) * 4;          // C row quad offset
    const int ro = 16 * w;                   // wave's row-tile base

    // M-fragment loader for segment s (both k-chunks, address-clamped; any
    // clamped-duplicate M-frag multiplies a zero-pad B-frag -> contributes 0)
    auto ldM = [&](int s, bf8& ah0, bf8& al0, bf8& ah1, bf8& al1) {
        const int n = C_N[s];
        const u16* __restrict__ Msh = Mh + C_OFF[s];
        const u16* __restrict__ Msl = Ml + C_OFF[s];
        const int rA  = ro + fr;
        const int rAc = (rA < n) ? rA : (n - 1);
        const int kx  = 32 + fk;
        const int kc1 = (kx <= n - 8) ? kx : (n - 8);
        ah0 = *(const bf8*)&Msh[(size_t)rAc * n + fk];
        al0 = *(const bf8*)&Msl[(size_t)rAc * n + fk];
        ah1 = *(const bf8*)&Msh[(size_t)rAc * n + kc1];
        al1 = *(const bf8*)&Msl[(size_t)rAc * n + kc1];
    };

    bf8 cah0, cal0, cah1, cal1, nah0, nal0, nah1, nal1;
    ldM(1, cah0, cal0, cah1, cal1);

    #pragma unroll 1
    for (int s = 1; s < NSEG7; ++s) {
        const int a0 = C_A0[s], j0 = C_J0[s], n = C_N[s];

        // B-frags from A_old (LDS); 2-range map, zero-pad rows kill k >= n
        const int kx = 32 + fk;
        const int b0 = a0 + fk;                       // k<32: pivot range
        const int b1 = (kx < n) ? (j0 + fk) : 128;    // k>=32: trailing or pad
        bf8 bh0 = *(const bf8*)&AhT[fr][b0];
        bf8 bl0 = *(const bf8*)&AlT[fr][b0];
        bf8 bh1 = *(const bf8*)&AhT[fr][b1];
        bf8 bl1 = *(const bf8*)&AlT[fr][b1];

        if (s + 1 < NSEG7) ldM(s + 1, nah0, nal0, nah1, nal1);

        const bool act = ro < n;             // wave-uniform
        f4 acc = {0, 0, 0, 0};
        if (act) {
            acc = __builtin_amdgcn_mfma_f32_16x16x32_bf16(cah0, bh0, acc, 0, 0, 0);
            acc = __builtin_amdgcn_mfma_f32_16x16x32_bf16(cah0, bl0, acc, 0, 0, 0);
            acc = __builtin_amdgcn_mfma_f32_16x16x32_bf16(cal0, bh0, acc, 0, 0, 0);
            acc = __builtin_amdgcn_mfma_f32_16x16x32_bf16(cal0, bl0, acc, 0, 0, 0);
            acc = __builtin_amdgcn_mfma_f32_16x16x32_bf16(cah1, bh1, acc, 0, 0, 0);
            acc = __builtin_amdgcn_mfma_f32_16x16x32_bf16(cah1, bl1, acc, 0, 0, 0);
            acc = __builtin_amdgcn_mfma_f32_16x16x32_bf16(cal1, bh1, acc, 0, 0, 0);
            acc = __builtin_amdgcn_mfma_f32_16x16x32_bf16(cal1, bl1, acc, 0, 0, 0);
        }

        __syncthreads();                     // all reads of old A complete

        const int rowq = ro + r4;            // quad never straddles the 32 boundary
        if (act && rowq < n) {
            const int rg = (rowq < 32) ? (a0 + rowq) : (j0 + rowq - 32);
            float v0 = acc[0], v1 = acc[1], v2 = acc[2], v3 = acc[3];
            u16 h0 = f2bf(v0), h1 = f2bf(v1), h2 = f2bf(v2), h3 = f2bf(v3);
            u16 l0 = f2bf(v0 - bf2f(h0)), l1 = f2bf(v1 - bf2f(h1));
            u16 l2 = f2bf(v2 - bf2f(h2)), l3 = f2bf(v3 - bf2f(h3));
            ushort4 hv; hv.x = h0; hv.y = h1; hv.z = h2; hv.w = h3;
            ushort4 lv; lv.x = l0; lv.y = l1; lv.z = l2; lv.w = l3;
            *(ushort4*)&AhT[fr][rg] = hv;
            *(ushort4*)&AlT[fr][rg] = lv;
        }
        __syncthreads();                     // new A visible

        cah0 = nah0; cal0 = nal0; cah1 = nah1; cal1 = nal1;
    }

    {   // output: Q = Ah + Al
        int c = tid & 15, rr = tid >> 4;
        float* o = out + (size_t)head * (DIM * DIM) + c0;
        for (int r = rr; r < DIM; r += 16)
            o[r * DIM + c] = bf2f(AhT[c][r]) + bf2f(AlT[c][r]);
    }
}

// ==== Fallback: monolithic Q-in-LDS chain (proven R7 structure), tiny-ws only ====
struct Row8 { f4 q0, q1, q2, q3; };
__device__ __forceinline__ void ldrow_u(Row8& R, const float* p) {
    const f4* c4 = (const f4*)p;
    R.q0 = c4[0]; R.q1 = c4[1]; R.q2 = c4[2]; R.q3 = c4[3];
}
#define QA(r, c) Q[(r)][ (c) ^ ((r) & 31) ]
#define ROTP(c, s, T, v) { float pt = p[T]; p[T] = fmaf((c), pt, (s) * (v)); \
                           (v) = fmaf((c), (v), -((s) * pt)); }
__device__ __forceinline__ void rot8q(const Row8& r, float p[8], float& v) {
    ROTP(r.q0.x, r.q0.y, 0, v) ROTP(r.q0.z, r.q0.w, 1, v)
    ROTP(r.q1.x, r.q1.y, 2, v) ROTP(r.q1.z, r.q1.w, 3, v)
    ROTP(r.q2.x, r.q2.y, 4, v) ROTP(r.q2.z, r.q2.w, 5, v)
    ROTP(r.q3.x, r.q3.y, 6, v) ROTP(r.q3.z, r.q3.w, 7, v)
}

__global__ __launch_bounds__(64, 1)
void chain_mono(const float* __restrict__ th_all, float* __restrict__ outp)
{
    __shared__ float Q[DIM][64];
    __shared__ __align__(16) float csx[56 + CSROWS * 16];

    const int lane = threadIdx.x;
    const int head = blockIdx.x & 63;
    const int cb   = blockIdx.x >> 6;
    const int col_glob = cb * 64 + lane;
    const float* __restrict__ th = th_all + head * NROT;

    for (int r = 0; r < DIM; ++r)
        QA(r, lane) = (r == col_glob) ? 1.0f : 0.0f;

    #pragma unroll 1
    for (int g = 0; g < 16; ++g) {
        const int a0  = 8 * g;
        const int ntr = 120 - a0;
        float p[8];
        const int nsub = (ntr > CSROWS) ? 2 : 1;
        #pragma unroll 1
        for (int sub = 0; sub < nsub; ++sub) {
            const int r0 = sub * CSROWS;
            const int nr = (ntr - r0) < CSROWS ? (ntr - r0) : CSROWS;
            const int ne = 8 * nr;
            __syncthreads();
            float thx[8];
            #pragma unroll
            for (int it = 0; it < 8; ++it) {
                if (it * 64 < ne) {
                    int e = lane + it * 64;
                    int t = e & 7, jr = r0 + (e >> 3);
                    thx[it] = th[tri_base(a0 + t) + jr + 7 - t];
                }
            }
            float thi = 0.0f;
            if (sub == 0 && lane < 28) {
                int t1 = 0, rem = lane;
                while (rem >= 7 - t1) { rem -= 7 - t1; ++t1; }
                int t2 = t1 + 1 + rem;
                thi = th[tri_base(a0 + t1) + (t2 - t1 - 1)];
            }
            #pragma unroll
            for (int it = 0; it < 8; ++it) {
                if (it * 64 < ne) {
                    int e = lane + it * 64;
                    float sn, cn; sincos_poly(thx[it], sn, cn);
                    csx[56 + 2 * e] = cn; csx[56 + 2 * e + 1] = sn;
                }
            }
            if (sub == 0 && lane < 28) {
                float sn, cn; sincos_poly(thi, sn, cn);
                csx[2 * lane] = cn; csx[2 * lane + 1] = sn;
            }
            __syncthreads();

            if (sub == 0) {
                #pragma unroll
                for (int t = 0; t < 8; ++t) p[t] = QA(a0 + t, lane);
                int idx = 0;
                #pragma unroll
                for (int t1 = 0; t1 < 8; ++t1) {
                    #pragma unroll
                    for (int t2 = t1 + 1; t2 < 8; ++t2) {
                        float c = csx[2 * idx], sn = csx[2 * idx + 1];
                        float pa = p[t1];
                        p[t1] = fmaf(c, pa,    sn * p[t2]);
                        p[t2] = fmaf(c, p[t2], -(sn * pa));
                        ++idx;
                    }
                }
            }
            if (nr > 0) {
                const float* cs = csx + 56;
                const int base = a0 + 8 + r0;
                Row8 A0, A1, B0, B1;
                float vA0, vA1, vB0, vB1;
                auto ldpair = [&](Row8& R, float& v, int r) {
                    ldrow_u(R, cs + 16 * r);
                    v = QA(base + r, lane);
                };
                ldpair(A0, vA0, 0); ldpair(A1, vA1, 1);
                #pragma unroll 1
                for (int r = 0; r < nr; r += 4) {
                    ldpair(B0, vB0, r + 2); ldpair(B1, vB1, r + 3);
                    rot8q(A0, p, vA0); rot8q(A1, p, vA1);
                    QA(base + r, lane)     = vA0;
                    QA(base + r + 1, lane) = vA1;
                    if (r + 4 < nr) { ldpair(A0, vA0, r + 4); ldpair(A1, vA1, r + 5); }
                    rot8q(B0, p, vB0); rot8q(B1, p, vB1);
                    QA(base + r + 2, lane) = vB0;
                    QA(base + r + 3, lane) = vB1;
                }
            }
        }
        #pragma unroll
        for (int t = 0; t < 8; ++t) QA(a0 + t, lane) = p[t];
    }

    __syncthreads();
    float* o = outp + head * (DIM * DIM) + col_glob;
    #pragma unroll 1
    for (int r = 0; r < DIM; ++r) o[r * DIM] = QA(r, lane);
}

extern "C" void kernel_launch(void* const* d_in, const int* in_sizes, int n_in,
                              void* d_out, int out_size, void* d_ws, size_t ws_size,
                              hipStream_t stream) {
    const float* thetas = (const float*)d_in[0];
    float* out = (float*)d_out;
    const size_t need = (size_t)NHEAD * MHEAD7 * 2 * sizeof(u16);  // 13.1 MB

    if (ws_size >= need) {
        u16* MhW = (u16*)d_ws;
        u16* MlW = MhW + (size_t)NHEAD * MHEAD7;
        chain7<<<dim3(NSEG7 * NHEAD), dim3(64), 0, stream>>>(thetas, MhW, MlW);
        compose7<<<dim3(8 * NHEAD), dim3(256), 0, stream>>>(MhW, MlW, out);
    } else {
        chain_mono<<<dim3(2 * NHEAD), dim3(64), 0, stream>>>(thetas, out);
    }
}